// Round 1
// baseline (46.258 us; speedup 1.0000x reference)
//
#include <hip/hip_runtime.h>
#include <math.h>

// out[b,t,d] = X[b,t,d] + PE[t,d]
//   PE[t,2i]   = sin(t / 10000^(2i/d))
//   PE[t,2i+1] = cos(t / 10000^(2i/d))
// B=8, T=4096, D=1024. Memory-bound: 256 MiB compulsory traffic.
// Each thread owns one float4 (2 sin/cos pairs) at a fixed (t, d0) and
// loops over the 8 batch slices, so trig is amortized 8x and the PE
// table never touches HBM.

__global__ __launch_bounds__(256) void pe_add_kernel(
    const float* __restrict__ X, float* __restrict__ out) {
    constexpr int B = 8, T = 4096, D = 1024;
    constexpr int D4 = D / 4;               // 256 float4 per row
    constexpr long long TD = (long long)T * D;

    const int idx = blockIdx.x * blockDim.x + threadIdx.x;  // 0 .. T*D/4-1
    const int t  = idx >> 8;                 // / D4
    const int c4 = idx & (D4 - 1);           // % D4
    const int d0 = c4 * 4;

    // inv_freq = 10000^(-2i/D) = exp2(-(2i/D) * log2(10000))
    const float L2_10000 = 13.287712379549449f;  // log2(10000)
    const float pos = (float)t;
    const float i0 = (float)(d0 >> 1);
    const float i1 = i0 + 1.0f;
    const float f0 = exp2f(-(2.0f * i0 / (float)D) * L2_10000);
    const float f1 = exp2f(-(2.0f * i1 / (float)D) * L2_10000);

    float s0, c0, s1, c1;
    sincosf(pos * f0, &s0, &c0);   // accurate version: pos*f0 up to 4095 rad
    sincosf(pos * f1, &s1, &c1);

    const float4 pe = make_float4(s0, c0, s1, c1);
    const long long base = (long long)t * D + d0;

    #pragma unroll
    for (int b = 0; b < B; ++b) {
        const long long off = (long long)b * TD + base;
        float4 x = *reinterpret_cast<const float4*>(X + off);
        x.x += pe.x; x.y += pe.y; x.z += pe.z; x.w += pe.w;
        *reinterpret_cast<float4*>(out + off) = x;
    }
}

extern "C" void kernel_launch(void* const* d_in, const int* in_sizes, int n_in,
                              void* d_out, int out_size, void* d_ws, size_t ws_size,
                              hipStream_t stream) {
    const float* X = (const float*)d_in[0];
    float* out = (float*)d_out;
    constexpr int T = 4096, D = 1024;
    constexpr int threads = 256;
    constexpr int total = T * D / 4;                 // one thread per float4 of a (t,d) row
    constexpr int blocks = (total + threads - 1) / threads;  // 4096
    pe_add_kernel<<<blocks, threads, 0, stream>>>(X, out);
}